// Round 21
// baseline (129.585 us; speedup 1.0000x reference)
//
#include <hip/hip_runtime.h>

// MultiHashEncoding: 2-level dense grid trilinear interpolation.
// r20: main 76.6us (fat slots: FETCH 87->38MB), k_bin ~35us (atomic line
// serialization: 1M atomics / 1056 lines ~ 950 serialized/line). r21:
// (1) NSUB 4->8 (2112 lines, serialization halved), CAPS 64; (2) main uses
// branchless gap-skip slot addressing (no dynamic-index scratch);
// (3) launch_bounds(256,8) so regalloc targets 8 blocks/CU @ 19.4KB LDS.
//
// Reference semantics (bit-exact corners): corner = floor(coords + OFFSET)
// with f32 add BEFORE floor; clip to [0,dim-1]; weight from CLIPPED corner.
//
// L0 extent derivation (key ix=(int)(px*15) == floor(cx) etc.): floor(cx) in
// {2bx,2bx+1} -> x ext 3; floor(cy) in [8by,8by+7] -> y ext 9; z ext 9.
// Binade +2 corners (weight ~ -1e-7) exceed by 1 -> LDS offset clamped,
// weight kept (err ~1e-6 << 8.1e-2). L1 NOT staged (emb1 4.8MB, L2-resident).

typedef float floatx4 __attribute__((ext_vector_type(4)));

#define KXB 8
#define KYB 17
#define KZB 31
#define NBINS (KXB * KYB * KZB)          // 4216
#define NSUB 8
#define CAPS 64                          // per-sub cap: mean 29.6 + 6.3 sigma
#define CAP_TOT (NSUB * CAPS)            // 512
#define CNT_DWORDS (NSUB * NBINS + 1)    // cnt[8*NBINS] + ovfc

#define L0X 3
#define L0Y 9
#define L0Z 9
#define L0CELLS (L0X * L0Y * L0Z)        // 243
#define CSTR 20   // dword cell stride: multiple of 4 (16B-aligned b128 reads),
                  // 80B spreads cell bases over all 8 aligned bank residues

__device__ __forceinline__ int point_key(float px, float py, float pz) {
    int ix = (int)(px * 15.0f);  ix = min(max(ix, 0), 15);
    int iy = (int)(py * 135.0f); iy = min(max(iy, 0), 135);
    int iz = (int)(pz * 240.0f); iz = min(max(iz, 0), 240);
    return ((ix >> 1) * KYB + (iy >> 3)) * KZB + (iz >> 3);
}

// ---------------- pass 0: zero counters ----------------
__global__ __launch_bounds__(256)
void k_zero(unsigned* __restrict__ cnt) {
    const int i = blockIdx.x * blockDim.x + threadIdx.x;
    if (i < CNT_DWORDS) cnt[i] = 0u;
}

// -------- pass 1: single-pass binning, 1 pt/thread, fat 16B slots --------
__global__ __launch_bounds__(256)
void k_bin(const float* __restrict__ pts, int n,
           unsigned* __restrict__ cnt, unsigned* __restrict__ ovfc,
           floatx4* __restrict__ slots, unsigned* __restrict__ ovf) {
    const int p = blockIdx.x * blockDim.x + threadIdx.x;
    if (p >= n) return;
    const size_t b = (size_t)p * 3;
    const float px = pts[b], py = pts[b + 1], pz = pts[b + 2];
    const int k = point_key(px, py, pz);
    const int sub = p & 7;                  // 8 cnt arrays = 8 L2 line sets
    const unsigned pos = atomicAdd(&cnt[sub * NBINS + k], 1u);
    if (pos < CAPS) {
        floatx4 rec = { px, py, pz, __int_as_float(p) };
        slots[(size_t)k * CAP_TOT + sub * CAPS + pos] = rec;
    } else {
        ovf[atomicAdd(ovfc, 1u)] = (unsigned)p;
    }
}

// ------- L0 corner setup (LDS dword offsets, clamped extents) -------
__device__ __forceinline__ void setup_lds(float cx, float cy, float cz,
                                          int xb, int yb, int zb, int d,
                                          int* __restrict__ off,
                                          float* __restrict__ w) {
    float gx[2] = { floorf(cx), floorf(cx + 1.0f) };
    float gy[2] = { floorf(cy), floorf(cy + 1.0f) };
    float gz[2] = { floorf(cz), floorf(cz + 1.0f) };
    float wx[2], wy[2], wz[2];
    int   xo[2], yo[2], zo[2];
#pragma unroll
    for (int b = 0; b < 2; ++b) {
        gx[b] = fminf(fmaxf(gx[b], 0.0f), 15.0f);
        gy[b] = fminf(fmaxf(gy[b], 0.0f), 135.0f);
        gz[b] = fminf(fmaxf(gz[b], 0.0f), 240.0f);
        wx[b] = 1.0f - fabsf(gx[b] - cx);       // weight from TRUE clipped corner
        wy[b] = 1.0f - fabsf(gy[b] - cy);
        wz[b] = 1.0f - fabsf(gz[b] - cz);
        // LDS offset clamped to staged extent (absorbs ~zero-weight binade +2)
        xo[b] = min((int)gx[b] - xb, L0X - 1) * (L0Y * L0Z * CSTR);
        yo[b] = min((int)gy[b] - yb, L0Y - 1) * (L0Z * CSTR);
        zo[b] = min((int)gz[b] - zb, L0Z - 1) * CSTR + d;
    }
    float wyz[4];
    int   yzo[4];
#pragma unroll
    for (int j = 0; j < 2; ++j)
#pragma unroll
        for (int k = 0; k < 2; ++k) {
            wyz[2 * j + k] = wy[j] * wz[k];
            yzo[2 * j + k] = yo[j] + zo[k];
        }
#pragma unroll
    for (int c = 0; c < 8; ++c) {
        const int i = (c >> 2) & 1, jk = c & 3;
        w[c]   = wx[i] * wyz[jk];
        off[c] = xo[i] + yzo[jk];
    }
}

// ---------------- global-gather setup (L1 + overflow + fallback) ------------
__device__ __forceinline__ void setup_glb(float cx, float cy, float cz,
                                          float tm1, float hm1, float wm1,
                                          int sh, int sw, int d,
                                          int* __restrict__ off,
                                          float* __restrict__ w) {
    float gx[2] = { floorf(cx), floorf(cx + 1.0f) };
    float gy[2] = { floorf(cy), floorf(cy + 1.0f) };
    float gz[2] = { floorf(cz), floorf(cz + 1.0f) };
    float wx[2], wy[2], wz[2];
    int   xo[2], yo[2], zo[2];
#pragma unroll
    for (int b = 0; b < 2; ++b) {
        gx[b] = fminf(fmaxf(gx[b], 0.0f), tm1);
        gy[b] = fminf(fmaxf(gy[b], 0.0f), hm1);
        gz[b] = fminf(fmaxf(gz[b], 0.0f), wm1);
        wx[b] = 1.0f - fabsf(gx[b] - cx);
        wy[b] = 1.0f - fabsf(gy[b] - cy);
        wz[b] = 1.0f - fabsf(gz[b] - cz);
        xo[b] = (int)gx[b] * sh;
        yo[b] = (int)gy[b] * sw;
        zo[b] = (int)gz[b] * 16 + d;
    }
    float wyz[4];
    int   yzo[4];
#pragma unroll
    for (int j = 0; j < 2; ++j)
#pragma unroll
        for (int k = 0; k < 2; ++k) {
            wyz[2 * j + k] = wy[j] * wz[k];
            yzo[2 * j + k] = yo[j] + zo[k];
        }
#pragma unroll
    for (int c = 0; c < 8; ++c) {
        const int i = (c >> 2) & 1, jk = c & 3;
        w[c]   = wx[i] * wyz[jk];
        off[c] = xo[i] + yzo[jk];
    }
}

__device__ __forceinline__ void encode_glb_quad(int p, int lane4,
                                                const float* __restrict__ pts,
                                                const float* __restrict__ emb0,
                                                const float* __restrict__ emb1,
                                                float* __restrict__ out) {
    const size_t b = (size_t)p * 3;
    const float px = pts[b], py = pts[b + 1], pz = pts[b + 2];
    int   o0[8], o1[8];
    float w0[8], w1[8];
    setup_glb(px * 15.0f, py * 135.0f, pz * 240.0f, 15.0f, 135.0f, 240.0f,
              136 * 241 * 16, 241 * 16, lane4, o0, w0);
    setup_glb(px * 8.0f, py * 68.0f, pz * 120.0f, 8.0f, 68.0f, 120.0f,
              69 * 121 * 16, 121 * 16, lane4, o1, w1);
    floatx4 a0 = {0,0,0,0}, a1 = {0,0,0,0};
#pragma unroll
    for (int c = 0; c < 8; ++c) a0 += w0[c] * *(const floatx4*)(emb0 + o0[c]);
#pragma unroll
    for (int c = 0; c < 8; ++c) a1 += w1[c] * *(const floatx4*)(emb1 + o1[c]);
    float* row = out + (size_t)p * 32 + lane4;
    __builtin_nontemporal_store(a0, (floatx4*)row);
    __builtin_nontemporal_store(a1, (floatx4*)(row + 16));
}

// ------- main: one block per bin, QUAD per point; L0 LDS, L1 from L2 -------
// Fat slots + branchless gap-skip addressing over the 8 sub-segments.
__global__ __launch_bounds__(256, 8)
void k_main_bins(const floatx4* __restrict__ slots,
                 const unsigned* __restrict__ cnt,
                 const unsigned* __restrict__ ovfc,
                 const unsigned* __restrict__ ovf,
                 const float* __restrict__ pts,
                 const float* __restrict__ emb0,
                 const float* __restrict__ emb1,
                 float* __restrict__ out) {
    // bijective XCD swizzle: 4216 = 8 * 527 exactly
    const int bin = (blockIdx.x & 7) * 527 + (blockIdx.x >> 3);

    unsigned ns[NSUB];
#pragma unroll
    for (int s = 0; s < NSUB; ++s) ns[s] = min(cnt[s * NBINS + bin], (unsigned)CAPS);
    unsigned cum1 = ns[0];
    unsigned cum2 = cum1 + ns[1];
    unsigned cum3 = cum2 + ns[2];
    unsigned cum4 = cum3 + ns[3];
    unsigned cum5 = cum4 + ns[4];
    unsigned cum6 = cum5 + ns[5];
    unsigned cum7 = cum6 + ns[6];
    const unsigned nt = cum7 + ns[7];

    __shared__ float lds0[L0CELLS * CSTR];   // 19.4 KB (L1 not staged)

    const int tid = threadIdx.x;
    const int d = (tid & 3) * 4;        // dword offset: this lane's 4 dims

    if (nt != 0) {                      // block-uniform branch: barriers safe
        const int bz = bin % KZB;
        const int t1 = bin / KZB;
        const int by = t1 % KYB;
        const int bx = t1 / KYB;
        const int x0 = bx * 2, y0 = by * 8, z0 = bz * 8;

        for (int idx = tid; idx < L0CELLS * 4; idx += 256) {
            const int cell = idx >> 2, q = (idx & 3) * 4;
            const int lz = cell % L0Z;
            const int t = cell / L0Z;
            const int ly = t % L0Y, lx = t / L0Y;
            const int gx = min(x0 + lx, 15), gy = min(y0 + ly, 135), gz = min(z0 + lz, 240);
            const floatx4 v = *(const floatx4*)(emb0 + ((size_t)(gx * 136 + gy) * 241 + gz) * 16 + q);
            *(floatx4*)(lds0 + cell * CSTR + q) = v;
        }
        __syncthreads();

        const int quad = tid >> 2;      // 64 quads/block
        const size_t sbase = (size_t)bin * CAP_TOT;

        // slot addr = sbase + t + sum over passed segments of (CAPS - ns):
        // branchless, all static indexing (no scratch).
        auto slot_of = [&](unsigned t) -> size_t {
            unsigned a = t;
            a += (t >= cum1) ? (CAPS - ns[0]) : 0u;
            a += (t >= cum2) ? (CAPS - ns[1]) : 0u;
            a += (t >= cum3) ? (CAPS - ns[2]) : 0u;
            a += (t >= cum4) ? (CAPS - ns[3]) : 0u;
            a += (t >= cum5) ? (CAPS - ns[4]) : 0u;
            a += (t >= cum6) ? (CAPS - ns[5]) : 0u;
            a += (t >= cum7) ? (CAPS - ns[6]) : 0u;
            return sbase + a;
        };

        unsigned t = quad;
        floatx4 rec = slots[slot_of(min(t, nt - 1))];
        while (t < nt) {
            // 1-ahead rec prefetch (4 VGPR: survives regalloc)
            const floatx4 recN = slots[slot_of(min(t + 64, nt - 1))];

            const float px = rec.x, py = rec.y, pz = rec.z;
            const int orig = __float_as_int(rec.w);

            int   o0[8], o1[8];
            float w0[8], w1[8];
            setup_glb(px * 8.0f, py * 68.0f, pz * 120.0f, 8.0f, 68.0f, 120.0f,
                      69 * 121 * 16, 121 * 16, d, o1, w1);
            floatx4 v1[8];
#pragma unroll
            for (int c = 0; c < 8; ++c) v1[c] = *(const floatx4*)(emb1 + o1[c]);
            setup_lds(px * 15.0f, py * 135.0f, pz * 240.0f, x0, y0, z0, d, o0, w0);

            floatx4 a0 = {0.f, 0.f, 0.f, 0.f}, a1 = {0.f, 0.f, 0.f, 0.f};
#pragma unroll
            for (int c = 0; c < 8; ++c) a0 += w0[c] * *(const floatx4*)(lds0 + o0[c]);
#pragma unroll
            for (int c = 0; c < 8; ++c) a1 += w1[c] * v1[c];

            // quad writes the 128B row as contiguous 64B chunks per instr
            float* row = out + (size_t)orig * 32 + d;
            __builtin_nontemporal_store(a0, (floatx4*)row);
            __builtin_nontemporal_store(a1, (floatx4*)(row + 16));

            rec = recN;
            t += 64;
        }
    }

    // overflow (folded): first 64 blocks grid-stride the list (empty in
    // practice; the global path is used for ALL corners of an overflow point)
    if (blockIdx.x < 64) {
        const unsigned total = *ovfc;
        for (unsigned i = (blockIdx.x * 256 + tid) >> 2; i < total;
             i += (64u * 256u) >> 2) {
            encode_glb_quad((int)ovf[i], d, pts, emb0, emb1, out);
        }
    }
}

// fallback (ws too small): direct gathers, 4 lanes/point
__global__ __launch_bounds__(256)
void k_main_plain(const float* __restrict__ pts,
                  const float* __restrict__ emb0,
                  const float* __restrict__ emb1,
                  float* __restrict__ out, int n) {
    const int g = blockIdx.x * blockDim.x + threadIdx.x;
    const int p = g >> 2;
    if (p >= n) return;
    encode_glb_quad(p, (g & 3) * 4, pts, emb0, emb1, out);
}

extern "C" void kernel_launch(void* const* d_in, const int* in_sizes, int n_in,
                              void* d_out, int out_size, void* d_ws, size_t ws_size,
                              hipStream_t stream) {
    const float* pts  = (const float*)d_in[0];
    const float* emb0 = (const float*)d_in[1];
    const float* emb1 = (const float*)d_in[2];
    float* out = (float*)d_out;
    const int n = in_sizes[0] / 3;

    const int block = 256;
    const int grid_pt = (n + block - 1) / block;                        // 1 pt/thread
    const int grid_4l = (int)(((long long)n * 4 + block - 1) / block);  // fallback
    const int grid_z  = (CNT_DWORDS + block - 1) / block;

    // workspace layout: cnt[8*NBINS] | ovfc | slots(16B) | ovf
    const size_t off_cnt   = 0;
    const size_t off_ovfc  = (size_t)NSUB * NBINS * 4;
    const size_t off_slots = ((off_ovfc + 4 + 15) & ~(size_t)15);
    const size_t off_ovf   = off_slots + (size_t)NBINS * CAP_TOT * 16;
    const size_t need      = off_ovf + (size_t)n * 4;

    if (ws_size < need) {
        k_main_plain<<<grid_4l, block, 0, stream>>>(pts, emb0, emb1, out, n);
        return;
    }

    char* ws = (char*)d_ws;
    unsigned* cnt   = (unsigned*)(ws + off_cnt);
    unsigned* ovfc  = (unsigned*)(ws + off_ovfc);
    floatx4*  slots = (floatx4*)(ws + off_slots);
    unsigned* ovf   = (unsigned*)(ws + off_ovf);

    k_zero<<<grid_z, block, 0, stream>>>(cnt);   // zeroes cnt + ovfc (contiguous)
    k_bin<<<grid_pt, block, 0, stream>>>(pts, n, cnt, ovfc, slots, ovf);
    k_main_bins<<<NBINS, block, 0, stream>>>(slots, cnt, ovfc, ovf,
                                             pts, emb0, emb1, out);
}

// Round 22
// 127.888 us; speedup vs baseline: 1.0133x; 1.0133x over previous
//
#include <hip/hip_runtime.h>

// MultiHashEncoding: 2-level dense grid trilinear interpolation.
// r21 post-mortem: launch_bounds(256,8) capped VGPR at 64 -> scratch spill
// (WRITE 130->172MB), main 77->98us. NSUB=8 k_bin was a win (~6us). r22:
// r20 main verbatim (bounds(256,4), no spill) + NSUB=8/CAPS=64 binning with
// branchless 8-segment gap-skip slot addressing.
//
// Reference semantics (bit-exact corners): corner = floor(coords + OFFSET)
// with f32 add BEFORE floor; clip to [0,dim-1]; weight from CLIPPED corner.
//
// L0 extent derivation (key ix=(int)(px*15) == floor(cx) etc.): floor(cx) in
// {2bx,2bx+1} -> x ext 3; floor(cy) in [8by,8by+7] -> y ext 9; z ext 9.
// Binade +2 corners (weight ~ -1e-7) exceed by 1 -> LDS offset clamped,
// weight kept (err ~1e-6 << 8.1e-2). L1 NOT staged (emb1 4.8MB, L2-resident).

typedef float floatx4 __attribute__((ext_vector_type(4)));

#define KXB 8
#define KYB 17
#define KZB 31
#define NBINS (KXB * KYB * KZB)          // 4216
#define NSUB 8
#define CAPS 64                          // per-sub cap: mean 29.6 + 6.3 sigma
#define CAP_TOT (NSUB * CAPS)            // 512
#define CNT_DWORDS (NSUB * NBINS + 1)    // cnt[8*NBINS] + ovfc

#define L0X 3
#define L0Y 9
#define L0Z 9
#define L0CELLS (L0X * L0Y * L0Z)        // 243
#define CSTR 20   // dword cell stride: multiple of 4 (16B-aligned b128 reads),
                  // 80B spreads cell bases over all 8 aligned bank residues

__device__ __forceinline__ int point_key(float px, float py, float pz) {
    int ix = (int)(px * 15.0f);  ix = min(max(ix, 0), 15);
    int iy = (int)(py * 135.0f); iy = min(max(iy, 0), 135);
    int iz = (int)(pz * 240.0f); iz = min(max(iz, 0), 240);
    return ((ix >> 1) * KYB + (iy >> 3)) * KZB + (iz >> 3);
}

// ---------------- pass 0: zero counters ----------------
__global__ __launch_bounds__(256)
void k_zero(unsigned* __restrict__ cnt) {
    const int i = blockIdx.x * blockDim.x + threadIdx.x;
    if (i < CNT_DWORDS) cnt[i] = 0u;
}

// -------- pass 1: single-pass binning, 1 pt/thread, fat 16B slots --------
__global__ __launch_bounds__(256)
void k_bin(const float* __restrict__ pts, int n,
           unsigned* __restrict__ cnt, unsigned* __restrict__ ovfc,
           floatx4* __restrict__ slots, unsigned* __restrict__ ovf) {
    const int p = blockIdx.x * blockDim.x + threadIdx.x;
    if (p >= n) return;
    const size_t b = (size_t)p * 3;
    const float px = pts[b], py = pts[b + 1], pz = pts[b + 2];
    const int k = point_key(px, py, pz);
    const int sub = p & 7;                  // 8 cnt arrays = 8 L2 line sets
    const unsigned pos = atomicAdd(&cnt[sub * NBINS + k], 1u);
    if (pos < CAPS) {
        floatx4 rec = { px, py, pz, __int_as_float(p) };
        slots[(size_t)k * CAP_TOT + sub * CAPS + pos] = rec;
    } else {
        ovf[atomicAdd(ovfc, 1u)] = (unsigned)p;
    }
}

// ------- L0 corner setup (LDS dword offsets, clamped extents) -------
__device__ __forceinline__ void setup_lds(float cx, float cy, float cz,
                                          int xb, int yb, int zb, int d,
                                          int* __restrict__ off,
                                          float* __restrict__ w) {
    float gx[2] = { floorf(cx), floorf(cx + 1.0f) };
    float gy[2] = { floorf(cy), floorf(cy + 1.0f) };
    float gz[2] = { floorf(cz), floorf(cz + 1.0f) };
    float wx[2], wy[2], wz[2];
    int   xo[2], yo[2], zo[2];
#pragma unroll
    for (int b = 0; b < 2; ++b) {
        gx[b] = fminf(fmaxf(gx[b], 0.0f), 15.0f);
        gy[b] = fminf(fmaxf(gy[b], 0.0f), 135.0f);
        gz[b] = fminf(fmaxf(gz[b], 0.0f), 240.0f);
        wx[b] = 1.0f - fabsf(gx[b] - cx);       // weight from TRUE clipped corner
        wy[b] = 1.0f - fabsf(gy[b] - cy);
        wz[b] = 1.0f - fabsf(gz[b] - cz);
        // LDS offset clamped to staged extent (absorbs ~zero-weight binade +2)
        xo[b] = min((int)gx[b] - xb, L0X - 1) * (L0Y * L0Z * CSTR);
        yo[b] = min((int)gy[b] - yb, L0Y - 1) * (L0Z * CSTR);
        zo[b] = min((int)gz[b] - zb, L0Z - 1) * CSTR + d;
    }
    float wyz[4];
    int   yzo[4];
#pragma unroll
    for (int j = 0; j < 2; ++j)
#pragma unroll
        for (int k = 0; k < 2; ++k) {
            wyz[2 * j + k] = wy[j] * wz[k];
            yzo[2 * j + k] = yo[j] + zo[k];
        }
#pragma unroll
    for (int c = 0; c < 8; ++c) {
        const int i = (c >> 2) & 1, jk = c & 3;
        w[c]   = wx[i] * wyz[jk];
        off[c] = xo[i] + yzo[jk];
    }
}

// ---------------- global-gather setup (L1 + overflow + fallback) ------------
__device__ __forceinline__ void setup_glb(float cx, float cy, float cz,
                                          float tm1, float hm1, float wm1,
                                          int sh, int sw, int d,
                                          int* __restrict__ off,
                                          float* __restrict__ w) {
    float gx[2] = { floorf(cx), floorf(cx + 1.0f) };
    float gy[2] = { floorf(cy), floorf(cy + 1.0f) };
    float gz[2] = { floorf(cz), floorf(cz + 1.0f) };
    float wx[2], wy[2], wz[2];
    int   xo[2], yo[2], zo[2];
#pragma unroll
    for (int b = 0; b < 2; ++b) {
        gx[b] = fminf(fmaxf(gx[b], 0.0f), tm1);
        gy[b] = fminf(fmaxf(gy[b], 0.0f), hm1);
        gz[b] = fminf(fmaxf(gz[b], 0.0f), wm1);
        wx[b] = 1.0f - fabsf(gx[b] - cx);
        wy[b] = 1.0f - fabsf(gy[b] - cy);
        wz[b] = 1.0f - fabsf(gz[b] - cz);
        xo[b] = (int)gx[b] * sh;
        yo[b] = (int)gy[b] * sw;
        zo[b] = (int)gz[b] * 16 + d;
    }
    float wyz[4];
    int   yzo[4];
#pragma unroll
    for (int j = 0; j < 2; ++j)
#pragma unroll
        for (int k = 0; k < 2; ++k) {
            wyz[2 * j + k] = wy[j] * wz[k];
            yzo[2 * j + k] = yo[j] + zo[k];
        }
#pragma unroll
    for (int c = 0; c < 8; ++c) {
        const int i = (c >> 2) & 1, jk = c & 3;
        w[c]   = wx[i] * wyz[jk];
        off[c] = xo[i] + yzo[jk];
    }
}

__device__ __forceinline__ void encode_glb_quad(int p, int lane4,
                                                const float* __restrict__ pts,
                                                const float* __restrict__ emb0,
                                                const float* __restrict__ emb1,
                                                float* __restrict__ out) {
    const size_t b = (size_t)p * 3;
    const float px = pts[b], py = pts[b + 1], pz = pts[b + 2];
    int   o0[8], o1[8];
    float w0[8], w1[8];
    setup_glb(px * 15.0f, py * 135.0f, pz * 240.0f, 15.0f, 135.0f, 240.0f,
              136 * 241 * 16, 241 * 16, lane4, o0, w0);
    setup_glb(px * 8.0f, py * 68.0f, pz * 120.0f, 8.0f, 68.0f, 120.0f,
              69 * 121 * 16, 121 * 16, lane4, o1, w1);
    floatx4 a0 = {0,0,0,0}, a1 = {0,0,0,0};
#pragma unroll
    for (int c = 0; c < 8; ++c) a0 += w0[c] * *(const floatx4*)(emb0 + o0[c]);
#pragma unroll
    for (int c = 0; c < 8; ++c) a1 += w1[c] * *(const floatx4*)(emb1 + o1[c]);
    float* row = out + (size_t)p * 32 + lane4;
    __builtin_nontemporal_store(a0, (floatx4*)row);
    __builtin_nontemporal_store(a1, (floatx4*)(row + 16));
}

// ------- main: one block per bin, QUAD per point; L0 LDS, L1 from L2 -------
// Fat slots + branchless gap-skip addressing; launch_bounds(256,4) (no spill).
__global__ __launch_bounds__(256, 4)
void k_main_bins(const floatx4* __restrict__ slots,
                 const unsigned* __restrict__ cnt,
                 const unsigned* __restrict__ ovfc,
                 const unsigned* __restrict__ ovf,
                 const float* __restrict__ pts,
                 const float* __restrict__ emb0,
                 const float* __restrict__ emb1,
                 float* __restrict__ out) {
    // bijective XCD swizzle: 4216 = 8 * 527 exactly
    const int bin = (blockIdx.x & 7) * 527 + (blockIdx.x >> 3);

    unsigned ns[NSUB];
#pragma unroll
    for (int s = 0; s < NSUB; ++s) ns[s] = min(cnt[s * NBINS + bin], (unsigned)CAPS);
    const unsigned cum1 = ns[0];
    const unsigned cum2 = cum1 + ns[1];
    const unsigned cum3 = cum2 + ns[2];
    const unsigned cum4 = cum3 + ns[3];
    const unsigned cum5 = cum4 + ns[4];
    const unsigned cum6 = cum5 + ns[5];
    const unsigned cum7 = cum6 + ns[6];
    const unsigned nt = cum7 + ns[7];

    __shared__ float lds0[L0CELLS * CSTR];   // 19.4 KB (L1 not staged)

    const int tid = threadIdx.x;
    const int d = (tid & 3) * 4;        // dword offset: this lane's 4 dims

    if (nt != 0) {                      // block-uniform branch: barriers safe
        const int bz = bin % KZB;
        const int t1 = bin / KZB;
        const int by = t1 % KYB;
        const int bx = t1 / KYB;
        const int x0 = bx * 2, y0 = by * 8, z0 = bz * 8;

        for (int idx = tid; idx < L0CELLS * 4; idx += 256) {
            const int cell = idx >> 2, q = (idx & 3) * 4;
            const int lz = cell % L0Z;
            const int t = cell / L0Z;
            const int ly = t % L0Y, lx = t / L0Y;
            const int gx = min(x0 + lx, 15), gy = min(y0 + ly, 135), gz = min(z0 + lz, 240);
            const floatx4 v = *(const floatx4*)(emb0 + ((size_t)(gx * 136 + gy) * 241 + gz) * 16 + q);
            *(floatx4*)(lds0 + cell * CSTR + q) = v;
        }
        __syncthreads();

        const int quad = tid >> 2;      // 64 quads/block
        const size_t sbase = (size_t)bin * CAP_TOT;

        // slot addr = sbase + t + sum over passed segments of (CAPS - ns):
        // branchless, all static indexing (no scratch).
        auto slot_of = [&](unsigned t) -> size_t {
            unsigned a = t;
            a += (t >= cum1) ? (CAPS - ns[0]) : 0u;
            a += (t >= cum2) ? (CAPS - ns[1]) : 0u;
            a += (t >= cum3) ? (CAPS - ns[2]) : 0u;
            a += (t >= cum4) ? (CAPS - ns[3]) : 0u;
            a += (t >= cum5) ? (CAPS - ns[4]) : 0u;
            a += (t >= cum6) ? (CAPS - ns[5]) : 0u;
            a += (t >= cum7) ? (CAPS - ns[6]) : 0u;
            return sbase + a;
        };

        unsigned t = quad;
        floatx4 rec = slots[slot_of(min(t, nt - 1))];
        while (t < nt) {
            // 1-ahead rec prefetch (4 VGPR: survives regalloc)
            const floatx4 recN = slots[slot_of(min(t + 64, nt - 1))];

            const float px = rec.x, py = rec.y, pz = rec.z;
            const int orig = __float_as_int(rec.w);

            int   o0[8], o1[8];
            float w0[8], w1[8];
            setup_glb(px * 8.0f, py * 68.0f, pz * 120.0f, 8.0f, 68.0f, 120.0f,
                      69 * 121 * 16, 121 * 16, d, o1, w1);
            floatx4 v1[8];
#pragma unroll
            for (int c = 0; c < 8; ++c) v1[c] = *(const floatx4*)(emb1 + o1[c]);
            setup_lds(px * 15.0f, py * 135.0f, pz * 240.0f, x0, y0, z0, d, o0, w0);

            floatx4 a0 = {0.f, 0.f, 0.f, 0.f}, a1 = {0.f, 0.f, 0.f, 0.f};
#pragma unroll
            for (int c = 0; c < 8; ++c) a0 += w0[c] * *(const floatx4*)(lds0 + o0[c]);
#pragma unroll
            for (int c = 0; c < 8; ++c) a1 += w1[c] * v1[c];

            // quad writes the 128B row as contiguous 64B chunks per instr
            float* row = out + (size_t)orig * 32 + d;
            __builtin_nontemporal_store(a0, (floatx4*)row);
            __builtin_nontemporal_store(a1, (floatx4*)(row + 16));

            rec = recN;
            t += 64;
        }
    }

    // overflow (folded): first 64 blocks grid-stride the list (empty in
    // practice; the global path is used for ALL corners of an overflow point)
    if (blockIdx.x < 64) {
        const unsigned total = *ovfc;
        for (unsigned i = (blockIdx.x * 256 + tid) >> 2; i < total;
             i += (64u * 256u) >> 2) {
            encode_glb_quad((int)ovf[i], d, pts, emb0, emb1, out);
        }
    }
}

// fallback (ws too small): direct gathers, 4 lanes/point
__global__ __launch_bounds__(256)
void k_main_plain(const float* __restrict__ pts,
                  const float* __restrict__ emb0,
                  const float* __restrict__ emb1,
                  float* __restrict__ out, int n) {
    const int g = blockIdx.x * blockDim.x + threadIdx.x;
    const int p = g >> 2;
    if (p >= n) return;
    encode_glb_quad(p, (g & 3) * 4, pts, emb0, emb1, out);
}

extern "C" void kernel_launch(void* const* d_in, const int* in_sizes, int n_in,
                              void* d_out, int out_size, void* d_ws, size_t ws_size,
                              hipStream_t stream) {
    const float* pts  = (const float*)d_in[0];
    const float* emb0 = (const float*)d_in[1];
    const float* emb1 = (const float*)d_in[2];
    float* out = (float*)d_out;
    const int n = in_sizes[0] / 3;

    const int block = 256;
    const int grid_pt = (n + block - 1) / block;                        // 1 pt/thread
    const int grid_4l = (int)(((long long)n * 4 + block - 1) / block);  // fallback
    const int grid_z  = (CNT_DWORDS + block - 1) / block;

    // workspace layout: cnt[8*NBINS] | ovfc | slots(16B) | ovf
    const size_t off_cnt   = 0;
    const size_t off_ovfc  = (size_t)NSUB * NBINS * 4;
    const size_t off_slots = ((off_ovfc + 4 + 15) & ~(size_t)15);
    const size_t off_ovf   = off_slots + (size_t)NBINS * CAP_TOT * 16;
    const size_t need      = off_ovf + (size_t)n * 4;

    if (ws_size < need) {
        k_main_plain<<<grid_4l, block, 0, stream>>>(pts, emb0, emb1, out, n);
        return;
    }

    char* ws = (char*)d_ws;
    unsigned* cnt   = (unsigned*)(ws + off_cnt);
    unsigned* ovfc  = (unsigned*)(ws + off_ovfc);
    floatx4*  slots = (floatx4*)(ws + off_slots);
    unsigned* ovf   = (unsigned*)(ws + off_ovf);

    k_zero<<<grid_z, block, 0, stream>>>(cnt);   // zeroes cnt + ovfc (contiguous)
    k_bin<<<grid_pt, block, 0, stream>>>(pts, n, cnt, ovfc, slots, ovf);
    k_main_bins<<<NBINS, block, 0, stream>>>(slots, cnt, ovfc, ovf,
                                             pts, emb0, emb1, out);
}

// Round 23
// 99.537 us; speedup vs baseline: 1.3019x; 1.2848x over previous
//
#include <hip/hip_runtime.h>

// MultiHashEncoding: 2-level dense grid trilinear interpolation.
// r22 post-mortem: 8-segment gap-skip added ~15 live regs -> per-iteration
// scratch traffic (+35MB WRITE) at same VGPR count; main 77->93us. r23:
// combine proven bests — r20 main VERBATIM (fat slots, 4-seg slot_of,
// bounds(256,4): 76.6us) + r16-shape k_bin (4pts/thread, vectorized loads,
// batched atomics) upgraded to fat 16B slot stores.
//
// Reference semantics (bit-exact corners): corner = floor(coords + OFFSET)
// with f32 add BEFORE floor; clip to [0,dim-1]; weight from CLIPPED corner.
//
// L0 extent derivation (key ix=(int)(px*15) == floor(cx) etc.): floor(cx) in
// {2bx,2bx+1} -> x ext 3; floor(cy) in [8by,8by+7] -> y ext 9; z ext 9.
// Binade +2 corners (weight ~ -1e-7) exceed by 1 -> LDS offset clamped,
// weight kept (err ~1e-6 << 8.1e-2). L1 NOT staged (emb1 4.8MB, L2-resident).

typedef float floatx4 __attribute__((ext_vector_type(4)));

#define KXB 8
#define KYB 17
#define KZB 31
#define NBINS (KXB * KYB * KZB)          // 4216
#define NSUB 4
#define CAPS 104                         // per-sub cap: mean 59.3 + 5.8 sigma
#define CAP_TOT (NSUB * CAPS)            // 416
#define CNT_DWORDS (NSUB * NBINS + 1)    // cnt[4*NBINS] + ovfc

#define L0X 3
#define L0Y 9
#define L0Z 9
#define L0CELLS (L0X * L0Y * L0Z)        // 243
#define CSTR 20   // dword cell stride: multiple of 4 (16B-aligned b128 reads),
                  // 80B spreads cell bases over all 8 aligned bank residues

__device__ __forceinline__ int point_key(float px, float py, float pz) {
    int ix = (int)(px * 15.0f);  ix = min(max(ix, 0), 15);
    int iy = (int)(py * 135.0f); iy = min(max(iy, 0), 135);
    int iz = (int)(pz * 240.0f); iz = min(max(iz, 0), 240);
    return ((ix >> 1) * KYB + (iy >> 3)) * KZB + (iz >> 3);
}

__device__ __forceinline__ void load4pts(const float* __restrict__ pts, int i4,
                                         float px[4], float py[4], float pz[4]) {
    const floatx4* v = (const floatx4*)(pts + (size_t)i4 * 3);
    const floatx4 a = v[0], b = v[1], c = v[2];
    px[0] = a.x; py[0] = a.y; pz[0] = a.z;
    px[1] = a.w; py[1] = b.x; pz[1] = b.y;
    px[2] = b.z; py[2] = b.w; pz[2] = c.x;
    px[3] = c.y; py[3] = c.z; pz[3] = c.w;
}

// ---------------- pass 0: zero counters ----------------
__global__ __launch_bounds__(256)
void k_zero(unsigned* __restrict__ cnt) {
    const int i = blockIdx.x * blockDim.x + threadIdx.x;
    if (i < CNT_DWORDS) cnt[i] = 0u;
}

// -------- pass 1: binning, 4 pts/thread, batched atomics, fat slots --------
__global__ __launch_bounds__(256)
void k_bin(const float* __restrict__ pts, int n,
           unsigned* __restrict__ cnt, unsigned* __restrict__ ovfc,
           floatx4* __restrict__ slots, unsigned* __restrict__ ovf) {
    const int i4 = (blockIdx.x * blockDim.x + threadIdx.x) * 4;
    if (i4 >= n) return;
    if (i4 + 3 < n) {
        float px[4], py[4], pz[4];
        load4pts(pts, i4, px, py, pz);
        int k[4];
#pragma unroll
        for (int j = 0; j < 4; ++j) k[j] = point_key(px[j], py[j], pz[j]);
        unsigned pos[4];
#pragma unroll
        for (int j = 0; j < 4; ++j)       // 4 different cnt arrays = 4 L2 lines
            pos[j] = atomicAdd(&cnt[j * NBINS + k[j]], 1u);
#pragma unroll
        for (int j = 0; j < 4; ++j) {
            if (pos[j] < CAPS) {
                floatx4 rec = { px[j], py[j], pz[j], __int_as_float(i4 + j) };
                slots[(size_t)k[j] * CAP_TOT + j * CAPS + pos[j]] = rec;
            } else {
                ovf[atomicAdd(ovfc, 1u)] = (unsigned)(i4 + j);
            }
        }
    } else {
        for (int j = 0; j < 4 && i4 + j < n; ++j) {
            const size_t b = (size_t)(i4 + j) * 3;
            const float px = pts[b], py = pts[b + 1], pz = pts[b + 2];
            const int k = point_key(px, py, pz);
            const unsigned pos = atomicAdd(&cnt[j * NBINS + k], 1u);
            if (pos < CAPS) {
                floatx4 rec = { px, py, pz, __int_as_float(i4 + j) };
                slots[(size_t)k * CAP_TOT + j * CAPS + pos] = rec;
            } else {
                ovf[atomicAdd(ovfc, 1u)] = (unsigned)(i4 + j);
            }
        }
    }
}

// ------- L0 corner setup (LDS dword offsets, clamped extents) -------
__device__ __forceinline__ void setup_lds(float cx, float cy, float cz,
                                          int xb, int yb, int zb, int d,
                                          int* __restrict__ off,
                                          float* __restrict__ w) {
    float gx[2] = { floorf(cx), floorf(cx + 1.0f) };
    float gy[2] = { floorf(cy), floorf(cy + 1.0f) };
    float gz[2] = { floorf(cz), floorf(cz + 1.0f) };
    float wx[2], wy[2], wz[2];
    int   xo[2], yo[2], zo[2];
#pragma unroll
    for (int b = 0; b < 2; ++b) {
        gx[b] = fminf(fmaxf(gx[b], 0.0f), 15.0f);
        gy[b] = fminf(fmaxf(gy[b], 0.0f), 135.0f);
        gz[b] = fminf(fmaxf(gz[b], 0.0f), 240.0f);
        wx[b] = 1.0f - fabsf(gx[b] - cx);       // weight from TRUE clipped corner
        wy[b] = 1.0f - fabsf(gy[b] - cy);
        wz[b] = 1.0f - fabsf(gz[b] - cz);
        // LDS offset clamped to staged extent (absorbs ~zero-weight binade +2)
        xo[b] = min((int)gx[b] - xb, L0X - 1) * (L0Y * L0Z * CSTR);
        yo[b] = min((int)gy[b] - yb, L0Y - 1) * (L0Z * CSTR);
        zo[b] = min((int)gz[b] - zb, L0Z - 1) * CSTR + d;
    }
    float wyz[4];
    int   yzo[4];
#pragma unroll
    for (int j = 0; j < 2; ++j)
#pragma unroll
        for (int k = 0; k < 2; ++k) {
            wyz[2 * j + k] = wy[j] * wz[k];
            yzo[2 * j + k] = yo[j] + zo[k];
        }
#pragma unroll
    for (int c = 0; c < 8; ++c) {
        const int i = (c >> 2) & 1, jk = c & 3;
        w[c]   = wx[i] * wyz[jk];
        off[c] = xo[i] + yzo[jk];
    }
}

// ---------------- global-gather setup (L1 + overflow + fallback) ------------
__device__ __forceinline__ void setup_glb(float cx, float cy, float cz,
                                          float tm1, float hm1, float wm1,
                                          int sh, int sw, int d,
                                          int* __restrict__ off,
                                          float* __restrict__ w) {
    float gx[2] = { floorf(cx), floorf(cx + 1.0f) };
    float gy[2] = { floorf(cy), floorf(cy + 1.0f) };
    float gz[2] = { floorf(cz), floorf(cz + 1.0f) };
    float wx[2], wy[2], wz[2];
    int   xo[2], yo[2], zo[2];
#pragma unroll
    for (int b = 0; b < 2; ++b) {
        gx[b] = fminf(fmaxf(gx[b], 0.0f), tm1);
        gy[b] = fminf(fmaxf(gy[b], 0.0f), hm1);
        gz[b] = fminf(fmaxf(gz[b], 0.0f), wm1);
        wx[b] = 1.0f - fabsf(gx[b] - cx);
        wy[b] = 1.0f - fabsf(gy[b] - cy);
        wz[b] = 1.0f - fabsf(gz[b] - cz);
        xo[b] = (int)gx[b] * sh;
        yo[b] = (int)gy[b] * sw;
        zo[b] = (int)gz[b] * 16 + d;
    }
    float wyz[4];
    int   yzo[4];
#pragma unroll
    for (int j = 0; j < 2; ++j)
#pragma unroll
        for (int k = 0; k < 2; ++k) {
            wyz[2 * j + k] = wy[j] * wz[k];
            yzo[2 * j + k] = yo[j] + zo[k];
        }
#pragma unroll
    for (int c = 0; c < 8; ++c) {
        const int i = (c >> 2) & 1, jk = c & 3;
        w[c]   = wx[i] * wyz[jk];
        off[c] = xo[i] + yzo[jk];
    }
}

__device__ __forceinline__ void encode_glb_quad(int p, int lane4,
                                                const float* __restrict__ pts,
                                                const float* __restrict__ emb0,
                                                const float* __restrict__ emb1,
                                                float* __restrict__ out) {
    const size_t b = (size_t)p * 3;
    const float px = pts[b], py = pts[b + 1], pz = pts[b + 2];
    int   o0[8], o1[8];
    float w0[8], w1[8];
    setup_glb(px * 15.0f, py * 135.0f, pz * 240.0f, 15.0f, 135.0f, 240.0f,
              136 * 241 * 16, 241 * 16, lane4, o0, w0);
    setup_glb(px * 8.0f, py * 68.0f, pz * 120.0f, 8.0f, 68.0f, 120.0f,
              69 * 121 * 16, 121 * 16, lane4, o1, w1);
    floatx4 a0 = {0,0,0,0}, a1 = {0,0,0,0};
#pragma unroll
    for (int c = 0; c < 8; ++c) a0 += w0[c] * *(const floatx4*)(emb0 + o0[c]);
#pragma unroll
    for (int c = 0; c < 8; ++c) a1 += w1[c] * *(const floatx4*)(emb1 + o1[c]);
    float* row = out + (size_t)p * 32 + lane4;
    __builtin_nontemporal_store(a0, (floatx4*)row);
    __builtin_nontemporal_store(a1, (floatx4*)(row + 16));
}

// ------- main: one block per bin, QUAD per point; L0 LDS, L1 from L2 -------
// Fat slots: one 16B quad-uniform load = coords+orig (no dependent pts load).
__global__ __launch_bounds__(256, 4)
void k_main_bins(const floatx4* __restrict__ slots,
                 const unsigned* __restrict__ cnt,
                 const unsigned* __restrict__ ovfc,
                 const unsigned* __restrict__ ovf,
                 const float* __restrict__ pts,
                 const float* __restrict__ emb0,
                 const float* __restrict__ emb1,
                 float* __restrict__ out) {
    // bijective XCD swizzle: 4216 = 8 * 527 exactly
    const int bin = (blockIdx.x & 7) * 527 + (blockIdx.x >> 3);
    const unsigned n0 = min(cnt[bin],             (unsigned)CAPS);
    const unsigned n1 = min(cnt[NBINS + bin],     (unsigned)CAPS);
    const unsigned n2 = min(cnt[2 * NBINS + bin], (unsigned)CAPS);
    const unsigned n3 = min(cnt[3 * NBINS + bin], (unsigned)CAPS);
    const unsigned c0 = n0, c1 = c0 + n1, c2 = c1 + n2, nt = c2 + n3;

    __shared__ float lds0[L0CELLS * CSTR];   // 19.4 KB (L1 not staged)

    const int tid = threadIdx.x;
    const int d = (tid & 3) * 4;        // dword offset: this lane's 4 dims

    if (nt != 0) {                      // block-uniform branch: barriers safe
        const int bz = bin % KZB;
        const int t1 = bin / KZB;
        const int by = t1 % KYB;
        const int bx = t1 / KYB;
        const int x0 = bx * 2, y0 = by * 8, z0 = bz * 8;

        for (int idx = tid; idx < L0CELLS * 4; idx += 256) {
            const int cell = idx >> 2, q = (idx & 3) * 4;
            const int lz = cell % L0Z;
            const int t = cell / L0Z;
            const int ly = t % L0Y, lx = t / L0Y;
            const int gx = min(x0 + lx, 15), gy = min(y0 + ly, 135), gz = min(z0 + lz, 240);
            const floatx4 v = *(const floatx4*)(emb0 + ((size_t)(gx * 136 + gy) * 241 + gz) * 16 + q);
            *(floatx4*)(lds0 + cell * CSTR + q) = v;
        }
        __syncthreads();

        const int quad = tid >> 2;      // 64 quads/block
        const size_t sbase = (size_t)bin * CAP_TOT;

        auto slot_of = [&](unsigned t) -> size_t {
            const unsigned seg = (t >= c0) + (t >= c1) + (t >= c2);
            const unsigned base = (seg == 0) ? 0u : ((seg == 1) ? c0 : ((seg == 2) ? c1 : c2));
            return sbase + seg * CAPS + (t - base);
        };

        unsigned t = quad;
        floatx4 rec = slots[slot_of(min(t, nt - 1))];
        while (t < nt) {
            // 1-ahead rec prefetch (4 VGPR: survives regalloc)
            const floatx4 recN = slots[slot_of(min(t + 64, nt - 1))];

            const float px = rec.x, py = rec.y, pz = rec.z;
            const int orig = __float_as_int(rec.w);

            int   o0[8], o1[8];
            float w0[8], w1[8];
            setup_glb(px * 8.0f, py * 68.0f, pz * 120.0f, 8.0f, 68.0f, 120.0f,
                      69 * 121 * 16, 121 * 16, d, o1, w1);
            floatx4 v1[8];
#pragma unroll
            for (int c = 0; c < 8; ++c) v1[c] = *(const floatx4*)(emb1 + o1[c]);
            setup_lds(px * 15.0f, py * 135.0f, pz * 240.0f, x0, y0, z0, d, o0, w0);

            floatx4 a0 = {0.f, 0.f, 0.f, 0.f}, a1 = {0.f, 0.f, 0.f, 0.f};
#pragma unroll
            for (int c = 0; c < 8; ++c) a0 += w0[c] * *(const floatx4*)(lds0 + o0[c]);
#pragma unroll
            for (int c = 0; c < 8; ++c) a1 += w1[c] * v1[c];

            // quad writes the 128B row as contiguous 64B chunks per instr
            float* row = out + (size_t)orig * 32 + d;
            __builtin_nontemporal_store(a0, (floatx4*)row);
            __builtin_nontemporal_store(a1, (floatx4*)(row + 16));

            rec = recN;
            t += 64;
        }
    }

    // overflow (folded): first 64 blocks grid-stride the list (empty in
    // practice; the global path is used for ALL corners of an overflow point)
    if (blockIdx.x < 64) {
        const unsigned total = *ovfc;
        for (unsigned i = (blockIdx.x * 256 + tid) >> 2; i < total;
             i += (64u * 256u) >> 2) {
            encode_glb_quad((int)ovf[i], d, pts, emb0, emb1, out);
        }
    }
}

// fallback (ws too small): direct gathers, 4 lanes/point
__global__ __launch_bounds__(256)
void k_main_plain(const float* __restrict__ pts,
                  const float* __restrict__ emb0,
                  const float* __restrict__ emb1,
                  float* __restrict__ out, int n) {
    const int g = blockIdx.x * blockDim.x + threadIdx.x;
    const int p = g >> 2;
    if (p >= n) return;
    encode_glb_quad(p, (g & 3) * 4, pts, emb0, emb1, out);
}

extern "C" void kernel_launch(void* const* d_in, const int* in_sizes, int n_in,
                              void* d_out, int out_size, void* d_ws, size_t ws_size,
                              hipStream_t stream) {
    const float* pts  = (const float*)d_in[0];
    const float* emb0 = (const float*)d_in[1];
    const float* emb1 = (const float*)d_in[2];
    float* out = (float*)d_out;
    const int n = in_sizes[0] / 3;

    const int block = 256;
    const int n4      = (n + 3) / 4;
    const int grid_p4 = (n4 + block - 1) / block;                       // 4 pts/thread
    const int grid_4l = (int)(((long long)n * 4 + block - 1) / block);  // fallback
    const int grid_z  = (CNT_DWORDS + block - 1) / block;

    // workspace layout: cnt[4*NBINS] | ovfc | slots(16B) | ovf
    const size_t off_cnt   = 0;
    const size_t off_ovfc  = (size_t)NSUB * NBINS * 4;
    const size_t off_slots = ((off_ovfc + 4 + 15) & ~(size_t)15);
    const size_t off_ovf   = off_slots + (size_t)NBINS * CAP_TOT * 16;
    const size_t need      = off_ovf + (size_t)n * 4;

    if (ws_size < need) {
        k_main_plain<<<grid_4l, block, 0, stream>>>(pts, emb0, emb1, out, n);
        return;
    }

    char* ws = (char*)d_ws;
    unsigned* cnt   = (unsigned*)(ws + off_cnt);
    unsigned* ovfc  = (unsigned*)(ws + off_ovfc);
    floatx4*  slots = (floatx4*)(ws + off_slots);
    unsigned* ovf   = (unsigned*)(ws + off_ovf);

    k_zero<<<grid_z, block, 0, stream>>>(cnt);   // zeroes cnt + ovfc (contiguous)
    k_bin<<<grid_p4, block, 0, stream>>>(pts, n, cnt, ovfc, slots, ovf);
    k_main_bins<<<NBINS, block, 0, stream>>>(slots, cnt, ovfc, ovf,
                                             pts, emb0, emb1, out);
}